// Round 10
// baseline (142.304 us; speedup 1.0000x reference)
//
#include <hip/hip_runtime.h>
#include <hip/hip_cooperative_groups.h>

namespace cg = cooperative_groups;

namespace {

constexpr int GV   = 48;
constexpr int NV   = 8;
constexpr int NH   = 27;
constexpr int NW   = 27;
constexpr int L    = NH * NW;     // 729
constexpr int C    = 1152;
constexpr int CD   = 288;
constexpr int NPTS = NV * L;      // 5832
constexpr int NVOX = GV * GV * GV;// 110592
constexpr int MAXP = 16;

// phase task counts
constexpr int NB_T     = (C / 32) * (CD / 32);        // 324 per matrix
constexpr int NB_ZC    = (NVOX + 255) / 256;          // 432
constexpr int NT_PREP  = 2 * NB_T + NB_ZC;            // 1080
constexpr int NT_G1    = ((NPTS + 31) / 32) * 3;      // 183*3 = 549
constexpr int NT_CONV  = NPTS / 8;                    // 729
constexpr int NT_G2    = ((NPTS + 95) / 96) * 12;     // 61*12 = 732
constexpr int GRID_MAX = 768;

constexpr int SMEM_BYTES = 32768;

typedef __attribute__((ext_vector_type(8))) short short8;
typedef __attribute__((ext_vector_type(4))) float f32x4;

__device__ __forceinline__ unsigned short f2bf(float x) {
    unsigned u = __float_as_uint(x);
    unsigned r = u + 0x7fffu + ((u >> 16) & 1u);   // round-to-nearest-even
    return (unsigned short)(r >> 16);
}
__device__ __forceinline__ float bf2f(unsigned short h) {
    return __uint_as_float(((unsigned)h) << 16);
}
__device__ __forceinline__ float gelu_tanh(float a) {
    float a3 = a * a * a;
    float inner = 0.7978845608028654f * (a + 0.044715f * a3);
    return 0.5f * a * (1.0f + tanhf(inner));
}
// LDS swizzles: [rows][32] / [rows][64] bf16 tiles, slot = 16B unit.
__device__ __forceinline__ int swz(int row, int slot) {
    return row * 32 + ((slot ^ ((row >> 1) & 3)) << 3);
}
__device__ __forceinline__ int swz64(int row, int slot) {
    return row * 64 + ((slot ^ (row & 7)) << 3);
}
// bijective XCD-chunked swizzle (m204), domain [0,nwg)
__device__ __forceinline__ int xcd_swz(int lid, int nwg) {
    const int q = nwg >> 3, r = nwg & 7;
    const int xcd = lid & 7, pos = lid >> 3;
    return (xcd < r ? xcd * (q + 1) : r * (q + 1) + (xcd - r) * q) + pos;
}

// ---------------- phase 0: weight transposes + zero cnt_i -------------------
__device__ void phase0_task(int task, const float* __restrict__ w_down,
                            const float* __restrict__ w_up,
                            unsigned short* __restrict__ wdt,
                            unsigned short* __restrict__ wut,
                            int* __restrict__ cnt_i, char* smem) {
    const int tid = threadIdx.x;
    if (task < 2 * NB_T) {
        float (*t)[33] = reinterpret_cast<float(*)[33]>(smem);
        const float* W; unsigned short* Wt; int K, N, kb, nb;
        if (task < NB_T) {
            W = w_down; Wt = wdt; K = C; N = CD;
            kb = (task % (C / 32)) * 32; nb = (task / (C / 32)) * 32;
        } else {
            int bb = task - NB_T;
            W = w_up; Wt = wut; K = CD; N = C;
            nb = (bb % (C / 32)) * 32; kb = (bb / (C / 32)) * 32;
        }
        __syncthreads();
#pragma unroll
        for (int i = 0; i < 4; ++i) {
            int r = (tid >> 5) + i * 8, c = tid & 31;
            t[r][c] = W[(size_t)(kb + r) * N + nb + c];
        }
        __syncthreads();
#pragma unroll
        for (int i = 0; i < 4; ++i) {
            int r = (tid >> 5) + i * 8, c = tid & 31;
            Wt[(size_t)(nb + r) * K + kb + c] = f2bf(t[c][r]);
        }
    } else {
        int i = (task - 2 * NB_T) * 256 + tid;
        if (i < NVOX) cnt_i[i] = 0;
    }
}

// ---------------- phase 1: GEMM1 (f32 A, inline cvt) + voxel-list build -----
// x = hs @ wdt^T. BM=32, BN=96, BK=64 (18 steps), 4 waves (2x2).
__device__ void gemm1_tile(int task, const float* __restrict__ A,
                           const unsigned short* __restrict__ Bt,
                           const int* __restrict__ coords,
                           int* __restrict__ cnt_i, int* __restrict__ vox_pts,
                           unsigned short* __restrict__ xout, char* smem) {
    constexpr int M = NPTS, N = CD, K = C;
    unsigned short (*As)[32 * 64] = reinterpret_cast<unsigned short(*)[32 * 64]>(smem);
    unsigned short (*Bs)[96 * 64] = reinterpret_cast<unsigned short(*)[96 * 64]>(smem + 8192);

    const int tid  = threadIdx.x;
    const int lane = tid & 63;
    const int wave = tid >> 6;
    const int wm   = wave >> 1;
    const int wn   = wave & 1;

    int lid = xcd_swz(task, NT_G1);
    const int m0 = (lid / 3) * 32;
    const int n0 = (lid % 3) * 96;

    const int  a_row  = tid >> 3;          // 0..31
    const int  a_slot = tid & 7;           // 0..7
    const bool avalid = (m0 + a_row) < M;
    const int  b_row  = tid >> 3;
    const int  b_slot = tid & 7;

    float4 af0, af1;
    short8 breg[3];

    auto LOAD = [&](int kt) {
        const int kb = kt * 64;
        af0 = make_float4(0.f, 0.f, 0.f, 0.f);
        af1 = af0;
        if (avalid) {
            const float* p = A + (size_t)(m0 + a_row) * K + kb + a_slot * 8;
            af0 = *reinterpret_cast<const float4*>(p);
            af1 = *reinterpret_cast<const float4*>(p + 4);
        }
#pragma unroll
        for (int i = 0; i < 3; ++i)
            breg[i] = *reinterpret_cast<const short8*>(
                Bt + (size_t)(n0 + b_row + i * 32) * K + kb + b_slot * 8);
    };
    auto STAGE = [&](int buf) {
        short8 h;
        h[0] = (short)f2bf(af0.x); h[1] = (short)f2bf(af0.y);
        h[2] = (short)f2bf(af0.z); h[3] = (short)f2bf(af0.w);
        h[4] = (short)f2bf(af1.x); h[5] = (short)f2bf(af1.y);
        h[6] = (short)f2bf(af1.z); h[7] = (short)f2bf(af1.w);
        *reinterpret_cast<short8*>(&As[buf][swz64(a_row, a_slot)]) = h;
#pragma unroll
        for (int i = 0; i < 3; ++i)
            *reinterpret_cast<short8*>(&Bs[buf][swz64(b_row + i * 32, b_slot)]) = breg[i];
    };

    f32x4 acc[3];
#pragma unroll
    for (int n = 0; n < 3; ++n) acc[n] = (f32x4){0.f, 0.f, 0.f, 0.f};

    const int nsteps = K / 64;      // 18
    __syncthreads();                // LDS reuse guard (stride loop / prior phase)
    LOAD(0);
    STAGE(0);
    LOAD(1);
    __syncthreads();

    const int kgrp = lane >> 4;
    const int lr   = lane & 15;

    for (int kt = 0; kt < nsteps; ++kt) {
        const int cur = kt & 1;
        short8 af[2], bf_[2][3];
#pragma unroll
        for (int s = 0; s < 2; ++s) {
            af[s] = *reinterpret_cast<const short8*>(
                &As[cur][swz64(wm * 16 + lr, s * 4 + kgrp)]);
#pragma unroll
            for (int n = 0; n < 3; ++n)
                bf_[s][n] = *reinterpret_cast<const short8*>(
                    &Bs[cur][swz64(wn * 48 + n * 16 + lr, s * 4 + kgrp)]);
        }
        if (kt + 1 < nsteps) {
            STAGE(cur ^ 1);
            if (kt + 2 < nsteps) LOAD(kt + 2);
        }
#pragma unroll
        for (int s = 0; s < 2; ++s)
#pragma unroll
            for (int n = 0; n < 3; ++n)
                acc[n] = __builtin_amdgcn_mfma_f32_16x16x32_bf16(af[s], bf_[s][n], acc[n], 0, 0, 0);
        if (kt + 1 < nsteps) __syncthreads();
    }

    const int rq = lane >> 4;
    const int rbase = m0 + wm * 16 + rq * 4;
#pragma unroll
    for (int n = 0; n < 3; ++n) {
        int col = n0 + wn * 48 + n * 16 + lr;
#pragma unroll
        for (int r = 0; r < 4; ++r) {
            int row = rbase + r;
            if (row < M) xout[(size_t)row * N + col] = f2bf(acc[n][r]);
        }
    }
    if (n0 == 0 && wn == 0 && lr == 0) {
#pragma unroll
        for (int r = 0; r < 4; ++r) {
            int row = rbase + r;
            if (row < M) {
                int c0 = coords[row * 3 + 0], c1 = coords[row * 3 + 1],
                    c2 = coords[row * 3 + 2];
                int fl = (c0 * GV + c1) * GV + c2;
                int slot = atomicAdd(&cnt_i[fl], 1);
                if (slot < MAXP) vox_pts[fl * MAXP + slot] = row;
            }
        }
    }
}

// ---------------- phase 2: conv3 via point lists + gelu (8 pts/task) --------
__device__ void conv3_task(int task, const int* __restrict__ coords,
                           const unsigned short* __restrict__ x,
                           const int* __restrict__ cnt_i,
                           const int* __restrict__ vox_pts,
                           const float* __restrict__ w3,
                           unsigned short* __restrict__ ptf, char* smem) {
    const int tid = threadIdx.x;
    const int p0  = task * 8;
    int*   nbr = reinterpret_cast<int*>(smem);          // [8*27]
    int*   ccc = nbr + 216;
    float* rcs = reinterpret_cast<float*>(ccc + 216);
    __syncthreads();                // LDS reuse guard
    if (tid < 216) {
        int pt = tid / 27, j = tid - pt * 27;
        int p  = p0 + pt;
        int dz = j / 9, rem = j - dz * 9, dy = rem / 3, dx = rem - dy * 3;
        int c0 = coords[p * 3 + 0], c1 = coords[p * 3 + 1], c2 = coords[p * 3 + 2];
        int z = c0 + dz - 1, y = c1 + dy - 1, x2 = c2 + dx - 1;
        bool ok = (unsigned)z < (unsigned)GV && (unsigned)y < (unsigned)GV &&
                  (unsigned)x2 < (unsigned)GV;
        int n = ok ? (z * GV + y) * GV + x2 : -1;
        int c = ok ? cnt_i[n] : 0;
        nbr[tid] = (c > 0) ? n : -1;
        ccc[tid] = c < MAXP ? c : MAXP;
        rcs[tid] = (c > 0) ? 1.0f / (float)c : 0.f;
    }
    __syncthreads();
#pragma unroll
    for (int i = 0; i < 9; ++i) {
        int u  = tid + i * 256;          // 0..2303
        int pt = u / 288;
        int ch = u - pt * 288;
        float acc = 0.f;
        for (int j = 0; j < 27; ++j) {
            int n = nbr[pt * 27 + j];
            if (n < 0) continue;
            int c = ccc[pt * 27 + j];
            float s = 0.f;
            for (int q = 0; q < c; ++q) {
                int p2 = vox_pts[n * MAXP + q];
                s += bf2f(x[(size_t)p2 * CD + ch]);
            }
            acc += w3[ch * 27 + j] * (s * rcs[pt * 27 + j]);
        }
        ptf[(size_t)(p0 + pt) * CD + ch] = f2bf(gelu_tanh(acc));
    }
}

// ---------------- phase 3: conv2 (8 pts/task) -------------------------------
__device__ void conv2_task(int task, const unsigned short* __restrict__ ptf,
                           const float* __restrict__ w2,
                           unsigned short* __restrict__ sm) {
    const int tid = threadIdx.x;
    const int p0  = task * 8;
#pragma unroll
    for (int i = 0; i < 9; ++i) {
        int u  = tid + i * 256;
        int pt = u / 288;
        int ch = u - pt * 288;
        int p  = p0 + pt;
        int v = p / L;
        int rem = p - v * L;
        int y = rem / NW;
        int xx = rem - y * NW;
        float acc = 0.f;
#pragma unroll
        for (int dy = 0; dy < 3; ++dy) {
            int yy = y + dy - 1;
            if ((unsigned)yy >= (unsigned)NH) continue;
#pragma unroll
            for (int dx = 0; dx < 3; ++dx) {
                int x3 = xx + dx - 1;
                if ((unsigned)x3 >= (unsigned)NW) continue;
                acc += w2[ch * 9 + dy * 3 + dx] *
                       bf2f(ptf[((size_t)v * L + yy * NW + x3) * CD + ch]);
            }
        }
        sm[(size_t)p * CD + ch] = f2bf(acc);
    }
}

// ---------------- phase 4: GEMM2  out = hs + sm @ wut^T ---------------------
// BM=96, BN=96, BK=32 (9 steps), 4 waves (2x2), wave tile 48x48 (MR=3).
__device__ void gemm2_tile(int task, const unsigned short* __restrict__ A,
                           const unsigned short* __restrict__ Bt,
                           const float* __restrict__ Cin,
                           float* __restrict__ Cout, char* smem) {
    constexpr int M = NPTS, N = C, K = CD;
    unsigned short (*As)[96 * 32] = reinterpret_cast<unsigned short(*)[96 * 32]>(smem);
    unsigned short (*Bs)[96 * 32] = reinterpret_cast<unsigned short(*)[96 * 32]>(smem + 12288);

    const int tid  = threadIdx.x;
    const int lane = tid & 63;
    const int wave = tid >> 6;
    const int wm   = wave >> 1;
    const int wn   = wave & 1;

    int lid = xcd_swz(task, NT_G2);
    const int m0 = (lid / 12) * 96;
    const int n0 = (lid % 12) * 96;

    const int  r0   = tid >> 2;            // 0..63
    const int  slot = tid & 3;
    const int  r1   = 64 + (tid >> 2);     // rows 64..95 (tid<128)
    const bool second = (tid < 128);
    const bool av0 = (m0 + r0) < M;
    const bool av1 = second && (m0 + r1) < M;

    short8 areg0, areg1, breg0, breg1;

    auto LOAD = [&](int kt) {
        const int kb = kt * 32;
        areg0 = (short8){0,0,0,0,0,0,0,0};
        if (av0)
            areg0 = *reinterpret_cast<const short8*>(A + (size_t)(m0 + r0) * K + kb + slot * 8);
        if (second) {
            areg1 = (short8){0,0,0,0,0,0,0,0};
            if (av1)
                areg1 = *reinterpret_cast<const short8*>(A + (size_t)(m0 + r1) * K + kb + slot * 8);
        }
        breg0 = *reinterpret_cast<const short8*>(Bt + (size_t)(n0 + r0) * K + kb + slot * 8);
        if (second)
            breg1 = *reinterpret_cast<const short8*>(Bt + (size_t)(n0 + r1) * K + kb + slot * 8);
    };
    auto STAGE = [&](int buf) {
        *reinterpret_cast<short8*>(&As[buf][swz(r0, slot)]) = areg0;
        *reinterpret_cast<short8*>(&Bs[buf][swz(r0, slot)]) = breg0;
        if (second) {
            *reinterpret_cast<short8*>(&As[buf][swz(r1, slot)]) = areg1;
            *reinterpret_cast<short8*>(&Bs[buf][swz(r1, slot)]) = breg1;
        }
    };

    f32x4 acc[3][3];
#pragma unroll
    for (int m = 0; m < 3; ++m)
#pragma unroll
        for (int n = 0; n < 3; ++n) acc[m][n] = (f32x4){0.f, 0.f, 0.f, 0.f};

    const int nsteps = K / 32;      // 9
    __syncthreads();                // LDS reuse guard
    LOAD(0);
    STAGE(0);
    LOAD(1);
    __syncthreads();

    const int kgrp = lane >> 4;
    const int lr   = lane & 15;

    for (int kt = 0; kt < nsteps; ++kt) {
        const int cur = kt & 1;
        short8 afrag[3], bfrag[3];
#pragma unroll
        for (int m = 0; m < 3; ++m)
            afrag[m] = *reinterpret_cast<const short8*>(
                &As[cur][swz(wm * 48 + m * 16 + lr, kgrp)]);
#pragma unroll
        for (int n = 0; n < 3; ++n)
            bfrag[n] = *reinterpret_cast<const short8*>(
                &Bs[cur][swz(wn * 48 + n * 16 + lr, kgrp)]);
        if (kt + 1 < nsteps) {
            STAGE(cur ^ 1);
            if (kt + 2 < nsteps) LOAD(kt + 2);
        }
#pragma unroll
        for (int m = 0; m < 3; ++m)
#pragma unroll
            for (int n = 0; n < 3; ++n)
                acc[m][n] = __builtin_amdgcn_mfma_f32_16x16x32_bf16(
                    afrag[m], bfrag[n], acc[m][n], 0, 0, 0);
        if (kt + 1 < nsteps) __syncthreads();
    }

    const int rq = lane >> 4;
#pragma unroll
    for (int m = 0; m < 3; ++m) {
        int rbase = m0 + wm * 48 + m * 16 + rq * 4;
#pragma unroll
        for (int n = 0; n < 3; ++n) {
            int col = n0 + wn * 48 + n * 16 + lr;
#pragma unroll
            for (int r = 0; r < 4; ++r) {
                int row = rbase + r;
                if (row < M)
                    Cout[(size_t)row * N + col] =
                        acc[m][n][r] + Cin[(size_t)row * N + col];
            }
        }
    }
}

// ---------------- cooperative mega-kernel -----------------------------------
__global__ __launch_bounds__(256, 3) void k_mega(const float* hs, const int* coords,
                                                 const float* w_down, const float* w3,
                                                 const float* w2, const float* w_up,
                                                 float* out, int* cnt_i, int* vox_pts,
                                                 unsigned short* xbuf, unsigned short* ptf,
                                                 unsigned short* smbuf, unsigned short* wdt,
                                                 unsigned short* wut) {
    __shared__ __align__(16) char smem[SMEM_BYTES];
    const int bid  = blockIdx.x;
    const int nblk = gridDim.x;
    cg::grid_group grid = cg::this_grid();

    for (int t = bid; t < NT_PREP; t += nblk)
        phase0_task(t, w_down, w_up, wdt, wut, cnt_i, smem);
    grid.sync();
    for (int t = bid; t < NT_G1; t += nblk)
        gemm1_tile(t, hs, wdt, coords, cnt_i, vox_pts, xbuf, smem);
    grid.sync();
    for (int t = bid; t < NT_CONV; t += nblk)
        conv3_task(t, coords, xbuf, cnt_i, vox_pts, w3, ptf, smem);
    grid.sync();
    for (int t = bid; t < NT_CONV; t += nblk)
        conv2_task(t, ptf, w2, smbuf);
    grid.sync();
    for (int t = bid; t < NT_G2; t += nblk)
        gemm2_tile(t, smbuf, wut, hs, out, smem);
}

// ---------------- fallback wrappers (5-kernel path) -------------------------
__global__ __launch_bounds__(256) void k_fb_prep(const float* w_down, const float* w_up,
                                                 unsigned short* wdt, unsigned short* wut,
                                                 int* cnt_i) {
    __shared__ __align__(16) char smem[SMEM_BYTES];
    phase0_task(blockIdx.x, w_down, w_up, wdt, wut, cnt_i, smem);
}
__global__ __launch_bounds__(256) void k_fb_g1(const float* hs, const unsigned short* wdt,
                                               const int* coords, int* cnt_i, int* vox_pts,
                                               unsigned short* xbuf) {
    __shared__ __align__(16) char smem[SMEM_BYTES];
    gemm1_tile(blockIdx.x, hs, wdt, coords, cnt_i, vox_pts, xbuf, smem);
}
__global__ __launch_bounds__(256) void k_fb_c3(const int* coords, const unsigned short* xbuf,
                                               const int* cnt_i, const int* vox_pts,
                                               const float* w3, unsigned short* ptf) {
    __shared__ __align__(16) char smem[SMEM_BYTES];
    conv3_task(blockIdx.x, coords, xbuf, cnt_i, vox_pts, w3, ptf, smem);
}
__global__ __launch_bounds__(256) void k_fb_c2(const unsigned short* ptf, const float* w2,
                                               unsigned short* smbuf) {
    conv2_task(blockIdx.x, ptf, w2, smbuf);
}
__global__ __launch_bounds__(256) void k_fb_g2(const unsigned short* smbuf,
                                               const unsigned short* wut,
                                               const float* hs, float* out) {
    __shared__ __align__(16) char smem[SMEM_BYTES];
    gemm2_tile(blockIdx.x, smbuf, wut, hs, out, smem);
}

}  // namespace

extern "C" void kernel_launch(void* const* d_in, const int* in_sizes, int n_in,
                              void* d_out, int out_size, void* d_ws, size_t ws_size,
                              hipStream_t stream) {
    const float* hs     = (const float*)d_in[0];
    const int*   coords = (const int*)d_in[1];
    const float* w_down = (const float*)d_in[2];
    const float* w3     = (const float*)d_in[3];
    const float* w2     = (const float*)d_in[4];
    const float* w_up   = (const float*)d_in[5];
    float* out = (float*)d_out;

    int* cnt_i   = (int*)d_ws;                          // NVOX
    int* vox_pts = cnt_i + NVOX;                        // NVOX*MAXP
    unsigned short* xbuf  = (unsigned short*)(vox_pts + (size_t)NVOX * MAXP);
    unsigned short* ptf   = xbuf + (size_t)NPTS * CD;
    unsigned short* smbuf = ptf + (size_t)NPTS * CD;
    unsigned short* wdt   = smbuf + (size_t)NPTS * CD;  // [CD][C]
    unsigned short* wut   = wdt + (size_t)CD * C;       // [C][CD]

    int maxb = 0;
    hipError_t qe = hipOccupancyMaxActiveBlocksPerMultiprocessor(
        &maxb, reinterpret_cast<const void*>(k_mega), 256, 0);

    if (qe == hipSuccess && maxb >= 2) {
        int grid = maxb * 256;
        if (grid > GRID_MAX) grid = GRID_MAX;
        void* args[] = {(void*)&hs, (void*)&coords, (void*)&w_down, (void*)&w3,
                        (void*)&w2, (void*)&w_up, (void*)&out, (void*)&cnt_i,
                        (void*)&vox_pts, (void*)&xbuf, (void*)&ptf, (void*)&smbuf,
                        (void*)&wdt, (void*)&wut};
        hipError_t le = hipLaunchCooperativeKernel(
            reinterpret_cast<const void*>(k_mega), dim3(grid), dim3(256), args, 0, stream);
        if (le == hipSuccess) return;
    }

    // fallback: proven 5-kernel path (same device functions)
    k_fb_prep<<<dim3(NT_PREP), dim3(256), 0, stream>>>(w_down, w_up, wdt, wut, cnt_i);
    k_fb_g1<<<dim3(NT_G1), dim3(256), 0, stream>>>(hs, wdt, coords, cnt_i, vox_pts, xbuf);
    k_fb_c3<<<dim3(NT_CONV), dim3(256), 0, stream>>>(coords, xbuf, cnt_i, vox_pts, w3, ptf);
    k_fb_c2<<<dim3(NT_CONV), dim3(256), 0, stream>>>(ptf, w2, smbuf);
    k_fb_g2<<<dim3(NT_G2), dim3(256), 0, stream>>>(smbuf, wut, hs, out);
}

// Round 11
// 78.862 us; speedup vs baseline: 1.8045x; 1.8045x over previous
//
#include <hip/hip_runtime.h>

namespace {

constexpr int GV   = 48;
constexpr int NV   = 8;
constexpr int NH   = 27;
constexpr int NW   = 27;
constexpr int L    = NH * NW;     // 729
constexpr int C    = 1152;
constexpr int CD   = 288;
constexpr int NPTS = NV * L;      // 5832
constexpr int NVOX = GV * GV * GV;// 110592
constexpr int MAXP = 16;          // max recorded points per voxel

typedef __attribute__((ext_vector_type(8))) short short8;
typedef __attribute__((ext_vector_type(4))) float f32x4;

__device__ __forceinline__ unsigned short f2bf(float x) {
    unsigned u = __float_as_uint(x);
    unsigned r = u + 0x7fffu + ((u >> 16) & 1u);   // round-to-nearest-even
    return (unsigned short)(r >> 16);
}
__device__ __forceinline__ float bf2f(unsigned short h) {
    return __uint_as_float(((unsigned)h) << 16);
}

// ---------------- combo kernel: weight transposes + zero cnt_i --------------
constexpr int NB_T    = (C / 32) * (CD / 32);         // 324 per matrix
constexpr int NB_ZC   = (NVOX + 255) / 256;           // 432
constexpr int B_T2    = NB_T;
constexpr int B_ZC    = 2 * NB_T;
constexpr int NB_ALL  = B_ZC + NB_ZC;                 // 1080

__global__ __launch_bounds__(256) void k_combo(const float* __restrict__ w_down,
                                               const float* __restrict__ w_up,
                                               unsigned short* __restrict__ wdt,
                                               unsigned short* __restrict__ wut,
                                               int* __restrict__ cnt_i) {
    const int b   = blockIdx.x;
    const int tid = threadIdx.x;
    if (b < B_ZC) {
        __shared__ float t[32][33];
        const float* W; unsigned short* Wt; int K, N, kb, nb;
        if (b < B_T2) {
            int bb = b;                        // w_down: K=C, N=CD
            W = w_down; Wt = wdt; K = C; N = CD;
            kb = (bb % (C / 32)) * 32; nb = (bb / (C / 32)) * 32;
        } else {
            int bb = b - B_T2;                 // w_up: K=CD, N=C
            W = w_up; Wt = wut; K = CD; N = C;
            nb = (bb % (C / 32)) * 32; kb = (bb / (C / 32)) * 32;
        }
#pragma unroll
        for (int i = 0; i < 4; ++i) {
            int r = (tid >> 5) + i * 8, c = tid & 31;
            t[r][c] = W[(size_t)(kb + r) * N + nb + c];
        }
        __syncthreads();
#pragma unroll
        for (int i = 0; i < 4; ++i) {
            int r = (tid >> 5) + i * 8, c = tid & 31;
            Wt[(size_t)(nb + r) * K + kb + c] = f2bf(t[c][r]);
        }
    } else {
        int i = (b - B_ZC) * 256 + tid;
        if (i < NVOX) cnt_i[i] = 0;
    }
}

__device__ __forceinline__ float gelu_tanh(float a) {
    float a3 = a * a * a;
    float inner = 0.7978845608028654f * (a + 0.044715f * a3);
    return 0.5f * a * (1.0f + tanhf(inner));
}

// Depthwise 3x3x3 conv at gathered voxels via a compacted per-block entry list:
// (point-row, tap j, 1/cnt) built once in LDS, then a flat unrolled MAC loop
// with independent loads (4 in flight). bf16 in/out.
__global__ __launch_bounds__(CD) void k_conv3_gather(const int* __restrict__ coords,
                                                     const unsigned short* __restrict__ x,
                                                     const int* __restrict__ cnt_i,
                                                     const int* __restrict__ vox_pts,
                                                     const float* __restrict__ w3,
                                                     unsigned short* __restrict__ ptf) {
    const int p = blockIdx.x;
    const int t = threadIdx.x;
    __shared__ int   ent_pj[27 * MAXP];    // (p2 << 5) | j
    __shared__ float ent_r[27 * MAXP];
    __shared__ int   nent_s;
    if (t == 0) nent_s = 0;
    __syncthreads();
    if (t < 27) {
        int dz = t / 9, rem = t - dz * 9, dy = rem / 3, dx = rem - dy * 3;
        int c0 = coords[p * 3 + 0], c1 = coords[p * 3 + 1], c2 = coords[p * 3 + 2];
        int z = c0 + dz - 1, y = c1 + dy - 1, x2 = c2 + dx - 1;
        if ((unsigned)z < (unsigned)GV && (unsigned)y < (unsigned)GV &&
            (unsigned)x2 < (unsigned)GV) {
            int n = (z * GV + y) * GV + x2;
            int c = cnt_i[n];
            if (c > 0) {
                int cc = c < MAXP ? c : MAXP;
                float r = 1.0f / (float)c;
                int base = atomicAdd(&nent_s, cc);
                for (int q = 0; q < cc; ++q) {
                    int p2 = vox_pts[n * MAXP + q];
                    ent_pj[base + q] = (p2 << 5) | t;
                    ent_r[base + q]  = r;
                }
            }
        }
    }
    __syncthreads();
    const int nent = nent_s;
    float acc = 0.f;
#pragma unroll 4
    for (int i = 0; i < nent; ++i) {
        int e  = ent_pj[i];
        int p2 = e >> 5, j = e & 31;
        acc += w3[t * 27 + j] * ent_r[i] * bf2f(x[(size_t)p2 * CD + t]);
    }
    ptf[(size_t)p * CD + t] = f2bf(gelu_tanh(acc));
}

// Depthwise 3x3 conv2d over (V,27,27,CD); bf16 in/out.
__global__ __launch_bounds__(CD) void k_conv2(const unsigned short* __restrict__ ptf,
                                              const float* __restrict__ w2,
                                              unsigned short* __restrict__ sm) {
    int p = blockIdx.x;
    int t = threadIdx.x;
    int v = p / L;
    int rem = p - v * L;
    int y = rem / NW;
    int x = rem - y * NW;
    float acc = 0.f;
#pragma unroll
    for (int dy = 0; dy < 3; ++dy) {
        int yy = y + dy - 1;
        if ((unsigned)yy >= (unsigned)NH) continue;
#pragma unroll
        for (int dx = 0; dx < 3; ++dx) {
            int xx = x + dx - 1;
            if ((unsigned)xx >= (unsigned)NW) continue;
            acc += w2[t * 9 + dy * 3 + dx] *
                   bf2f(ptf[((size_t)v * L + yy * NW + xx) * CD + t]);
        }
    }
    sm[(size_t)p * CD + t] = f2bf(acc);
}

// LDS swizzles: [rows][32] and [rows][64] bf16 tiles, slot = 16B unit.
__device__ __forceinline__ int swz(int row, int slot) {
    return row * 32 + ((slot ^ ((row >> 1) & 3)) << 3);
}
__device__ __forceinline__ int swz64(int row, int slot) {
    return row * 64 + ((slot ^ (row & 7)) << 3);
}

// bijective XCD-chunked block swizzle (m204)
__device__ __forceinline__ int xcd_swz(int lid, int nwg) {
    const int q = nwg >> 3, r = nwg & 7;
    const int xcd = lid & 7, pos = lid >> 3;
    return (xcd < r ? xcd * (q + 1) : r * (q + 1) + (xcd - r) * q) + pos;
}

// GEMM1: x = hs @ wdt^T (f32 A, inline cvt), dense bf16 output + voxel-list
// append (n0==0 blocks). BM=32, BN=96, BK=64 (18 steps), 4 waves (2x2),
// double-buffered LDS, register prefetch, one barrier per K-step, XCD swizzle.
__global__ __launch_bounds__(256) void k_gemm1(const float* __restrict__ A,
                                               const unsigned short* __restrict__ Bt,
                                               const int* __restrict__ coords,
                                               int* __restrict__ cnt_i,
                                               int* __restrict__ vox_pts,
                                               unsigned short* __restrict__ xout,
                                               int M, int N, int K) {
    __shared__ unsigned short As[2][32 * 64];   // 4 KB each
    __shared__ unsigned short Bs[2][96 * 64];   // 12 KB each

    const int tid  = threadIdx.x;
    const int lane = tid & 63;
    const int wave = tid >> 6;
    const int wm   = wave >> 1;
    const int wn   = wave & 1;

    const int nwg = gridDim.x * gridDim.y;
    int lid = xcd_swz(blockIdx.y * gridDim.x + blockIdx.x, nwg);
    const int m0 = (lid / gridDim.x) * 32;
    const int n0 = (lid % gridDim.x) * 96;

    const int  a_row  = tid >> 3;
    const int  a_slot = tid & 7;
    const bool avalid = (m0 + a_row) < M;
    const int  b_row  = tid >> 3;
    const int  b_slot = tid & 7;

    float4 af0, af1;
    short8 breg[3];

    auto LOAD = [&](int kt) {
        const int kb = kt * 64;
        af0 = make_float4(0.f, 0.f, 0.f, 0.f);
        af1 = af0;
        if (avalid) {
            const float* p = A + (size_t)(m0 + a_row) * K + kb + a_slot * 8;
            af0 = *reinterpret_cast<const float4*>(p);
            af1 = *reinterpret_cast<const float4*>(p + 4);
        }
#pragma unroll
        for (int i = 0; i < 3; ++i)
            breg[i] = *reinterpret_cast<const short8*>(
                Bt + (size_t)(n0 + b_row + i * 32) * K + kb + b_slot * 8);
    };

    auto STAGE = [&](int buf) {
        short8 h;
        h[0] = (short)f2bf(af0.x); h[1] = (short)f2bf(af0.y);
        h[2] = (short)f2bf(af0.z); h[3] = (short)f2bf(af0.w);
        h[4] = (short)f2bf(af1.x); h[5] = (short)f2bf(af1.y);
        h[6] = (short)f2bf(af1.z); h[7] = (short)f2bf(af1.w);
        *reinterpret_cast<short8*>(&As[buf][swz64(a_row, a_slot)]) = h;
#pragma unroll
        for (int i = 0; i < 3; ++i)
            *reinterpret_cast<short8*>(&Bs[buf][swz64(b_row + i * 32, b_slot)]) = breg[i];
    };

    f32x4 acc[3];
#pragma unroll
    for (int n = 0; n < 3; ++n) acc[n] = (f32x4){0.f, 0.f, 0.f, 0.f};

    const int nsteps = K / 64;      // 18
    LOAD(0);
    STAGE(0);
    LOAD(1);
    __syncthreads();

    const int kgrp = lane >> 4;
    const int lr   = lane & 15;

    for (int kt = 0; kt < nsteps; ++kt) {
        const int cur = kt & 1;
        short8 af[2], bf_[2][3];
#pragma unroll
        for (int s = 0; s < 2; ++s) {
            af[s] = *reinterpret_cast<const short8*>(
                &As[cur][swz64(wm * 16 + lr, s * 4 + kgrp)]);
#pragma unroll
            for (int n = 0; n < 3; ++n)
                bf_[s][n] = *reinterpret_cast<const short8*>(
                    &Bs[cur][swz64(wn * 48 + n * 16 + lr, s * 4 + kgrp)]);
        }
        if (kt + 1 < nsteps) {
            STAGE(cur ^ 1);
            if (kt + 2 < nsteps) LOAD(kt + 2);
        }
#pragma unroll
        for (int s = 0; s < 2; ++s)
#pragma unroll
            for (int n = 0; n < 3; ++n)
                acc[n] = __builtin_amdgcn_mfma_f32_16x16x32_bf16(af[s], bf_[s][n], acc[n], 0, 0, 0);
        if (kt + 1 < nsteps) __syncthreads();
    }

    const int rq = lane >> 4;
    const int rbase = m0 + wm * 16 + rq * 4;
#pragma unroll
    for (int n = 0; n < 3; ++n) {
        int col = n0 + wn * 48 + n * 16 + lr;
#pragma unroll
        for (int r = 0; r < 4; ++r) {
            int row = rbase + r;
            if (row < M) xout[(size_t)row * N + col] = f2bf(acc[n][r]);
        }
    }
    if (n0 == 0 && wn == 0 && lr == 0) {
#pragma unroll
        for (int r = 0; r < 4; ++r) {
            int row = rbase + r;
            if (row < M) {
                int c0 = coords[row * 3 + 0], c1 = coords[row * 3 + 1],
                    c2 = coords[row * 3 + 2];
                int fl = (c0 * GV + c1) * GV + c2;
                int slot = atomicAdd(&cnt_i[fl], 1);
                if (slot < MAXP) vox_pts[fl * MAXP + slot] = row;
            }
        }
    }
}

// Plain bf16 GEMM2: out = Cin + A @ Bt^T. BM=64, BN=96, BK=32, 4 waves (2x2).
__global__ __launch_bounds__(256) void k_gemm2(const unsigned short* __restrict__ A,
                                               const unsigned short* __restrict__ Bt,
                                               const float* __restrict__ Cin,
                                               float* __restrict__ Cout,
                                               int M, int N, int K) {
    __shared__ unsigned short As[2][64 * 32];
    __shared__ unsigned short Bs[2][96 * 32];

    const int tid  = threadIdx.x;
    const int lane = tid & 63;
    const int wave = tid >> 6;
    const int wm   = wave >> 1;
    const int wn   = wave & 1;

    const int nwg = gridDim.x * gridDim.y;
    int lid = xcd_swz(blockIdx.y * gridDim.x + blockIdx.x, nwg);
    const int m0 = (lid / gridDim.x) * 64;
    const int n0 = (lid % gridDim.x) * 96;

    const int  a_row  = tid >> 2;
    const int  a_slot = tid & 3;
    const bool avalid = (m0 + a_row) < M;

    const int b0_row = tid >> 2, b0_slot = tid & 3;
    const int b1_row = 64 + (tid >> 2);
    const bool has_b1 = (tid < 128);

    short8 areg, breg0, breg1;

    auto LOAD = [&](int kt) {
        const int kb = kt * 32;
        areg = (short8){0,0,0,0,0,0,0,0};
        if (avalid)
            areg = *reinterpret_cast<const short8*>(A + (size_t)(m0 + a_row) * K + kb + a_slot * 8);
        breg0 = *reinterpret_cast<const short8*>(Bt + (size_t)(n0 + b0_row) * K + kb + b0_slot * 8);
        if (has_b1)
            breg1 = *reinterpret_cast<const short8*>(Bt + (size_t)(n0 + b1_row) * K + kb + b0_slot * 8);
    };

    auto STAGE = [&](int buf) {
        *reinterpret_cast<short8*>(&As[buf][swz(a_row, a_slot)]) = areg;
        *reinterpret_cast<short8*>(&Bs[buf][swz(b0_row, b0_slot)]) = breg0;
        if (has_b1)
            *reinterpret_cast<short8*>(&Bs[buf][swz(b1_row, b0_slot)]) = breg1;
    };

    f32x4 acc[2][3];
#pragma unroll
    for (int m = 0; m < 2; ++m)
#pragma unroll
        for (int n = 0; n < 3; ++n) acc[m][n] = (f32x4){0.f, 0.f, 0.f, 0.f};

    const int nsteps = K / 32;
    LOAD(0);
    STAGE(0);
    LOAD(1);
    __syncthreads();

    const int kgrp = lane >> 4;
    const int lr   = lane & 15;

    for (int kt = 0; kt < nsteps; ++kt) {
        const int cur = kt & 1;
        short8 afrag[2], bfrag[3];
#pragma unroll
        for (int m = 0; m < 2; ++m) {
            int r = wm * 32 + m * 16 + lr;
            afrag[m] = *reinterpret_cast<const short8*>(&As[cur][swz(r, kgrp)]);
        }
#pragma unroll
        for (int n = 0; n < 3; ++n) {
            int c = wn * 48 + n * 16 + lr;
            bfrag[n] = *reinterpret_cast<const short8*>(&Bs[cur][swz(c, kgrp)]);
        }
        if (kt + 1 < nsteps) {
            STAGE(cur ^ 1);
            if (kt + 2 < nsteps) LOAD(kt + 2);
        }
#pragma unroll
        for (int m = 0; m < 2; ++m)
#pragma unroll
            for (int n = 0; n < 3; ++n)
                acc[m][n] = __builtin_amdgcn_mfma_f32_16x16x32_bf16(
                    afrag[m], bfrag[n], acc[m][n], 0, 0, 0);
        if (kt + 1 < nsteps) __syncthreads();
    }

    const int rq = lane >> 4;
#pragma unroll
    for (int m = 0; m < 2; ++m) {
        int rbase = m0 + wm * 32 + m * 16 + rq * 4;
#pragma unroll
        for (int n = 0; n < 3; ++n) {
            int col = n0 + wn * 48 + n * 16 + lr;
#pragma unroll
            for (int r = 0; r < 4; ++r) {
                int row = rbase + r;
                if (row < M)
                    Cout[(size_t)row * N + col] =
                        acc[m][n][r] + Cin[(size_t)row * N + col];
            }
        }
    }
}

}  // namespace

extern "C" void kernel_launch(void* const* d_in, const int* in_sizes, int n_in,
                              void* d_out, int out_size, void* d_ws, size_t ws_size,
                              hipStream_t stream) {
    const float* hs     = (const float*)d_in[0];
    const int*   coords = (const int*)d_in[1];
    const float* w_down = (const float*)d_in[2];
    const float* w3     = (const float*)d_in[3];
    const float* w2     = (const float*)d_in[4];
    const float* w_up   = (const float*)d_in[5];
    float* out = (float*)d_out;

    int* cnt_i   = (int*)d_ws;                          // NVOX int
    int* vox_pts = cnt_i + NVOX;                        // NVOX*MAXP int
    unsigned short* xbuf  = (unsigned short*)(vox_pts + (size_t)NVOX * MAXP); // NPTS*CD
    unsigned short* ptf   = xbuf + (size_t)NPTS * CD;   // NPTS*CD bf16
    unsigned short* smbuf = ptf + (size_t)NPTS * CD;    // NPTS*CD bf16
    unsigned short* wdt   = smbuf + (size_t)NPTS * CD;  // [CD][C] bf16
    unsigned short* wut   = wdt + (size_t)CD * C;       // [C][CD] bf16

    // 1. prep: weight transposes + zero cnt_i
    k_combo<<<dim3(NB_ALL), dim3(256), 0, stream>>>(w_down, w_up, wdt, wut, cnt_i);

    // 2. GEMM1: dense bf16 x + voxel point-list build
    k_gemm1<<<dim3(CD / 96, (NPTS + 31) / 32), dim3(256), 0, stream>>>(
        hs, wdt, coords, cnt_i, vox_pts, xbuf, NPTS, CD, C);

    // 3. depthwise conv3d (mean via point lists, compacted-entry MAC) + gelu
    k_conv3_gather<<<dim3(NPTS), dim3(CD), 0, stream>>>(
        coords, xbuf, cnt_i, vox_pts, w3, ptf);

    // 4. depthwise conv2d (bf16 in/out)
    k_conv2<<<dim3(NPTS), dim3(CD), 0, stream>>>(ptf, w2, smbuf);

    // 5. out = hs + sm @ w_up
    k_gemm2<<<dim3(C / 96, (NPTS + 63) / 64), dim3(256), 0, stream>>>(
        smbuf, wut, hs, out, NPTS, C, CD);
}